// Round 7
// baseline (323.235 us; speedup 1.0000x reference)
//
#include <hip/hip_runtime.h>

// ---------------------------------------------------------------------------
// MoE top-2 sparse. MI355X (gfx950). B=2,L=1024,D=768,E=16,F=3072,K=2
// GEMM: block = whole expert (BM=384) x BN=96, BK=32, 512 thr (8 waves,
// 4m x 2n, wave tile 96x48 = 6x3 frags of mfma 16x16x32). LDS 60 KB dbuf ->
// 2 blocks/CU (the R4-R6 1-block/CU barrier idle was the wall: 334 TF = the
// known 2-barrier single-block ceiling). Reg-staged (T14), XOR swizzle
// slot ^= (row>>1)&3 on 64B rows (derived conflict-free). Weights stream
// HBM/L3 exactly once; A panels L2-resident per XCD (bid%8==e%8).
// fc2: K=3072 as 4x768 k-splits -> bf16 partial planes, ONE 512-block launch.
// Pad-band skip via meta[] (waves with all rows >= cnt skip MFMA+epilogue).
// ---------------------------------------------------------------------------

#define D_      768
#define E_      16
#define F_      3072
#define NTOK    2048
#define NROWS   4096
#define SEG     384
#define MAXROWS 6144
#define BK      32
#define BNW     96

typedef __attribute__((ext_vector_type(2))) unsigned int   u32x2;
typedef __attribute__((ext_vector_type(4))) unsigned int   u32x4;
typedef __attribute__((ext_vector_type(8))) unsigned short u16x8;
typedef __attribute__((ext_vector_type(8))) short          v8bf;
typedef __attribute__((ext_vector_type(4))) float          f32x4;

static __device__ inline unsigned short f2bf(float f) {
    unsigned u = __builtin_bit_cast(unsigned, f);
    u += 0x7fffu + ((u >> 16) & 1u);      // RNE
    return (unsigned short)(u >> 16);
}
static __device__ __forceinline__ unsigned cvt_pk_bf16(float lo, float hi) {
    unsigned r;
    asm("v_cvt_pk_bf16_f32 %0, %1, %2" : "=v"(r) : "v"(lo), "v"(hi));
    return r;
}

// ---------------------------------------------------------------------------
// 1. Router: softmax over 16, top-2 (ties -> lowest idx), gates = raw probs
// ---------------------------------------------------------------------------
__global__ void router_kernel(const float* __restrict__ x, const float* __restrict__ wr,
                              int* __restrict__ idx, float* __restrict__ gate) {
    const int tok  = blockIdx.x;
    const int lane = threadIdx.x;          // 64
    const float* xr = x + (size_t)tok * D_;

    float xv[12];
#pragma unroll
    for (int j = 0; j < 12; ++j) xv[j] = xr[lane + 64 * j];

    float lg[E_];
#pragma unroll
    for (int e = 0; e < E_; ++e) {
        const float* w = wr + (size_t)e * D_;
        float acc = 0.f;
#pragma unroll
        for (int j = 0; j < 12; ++j) acc += xv[j] * w[lane + 64 * j];
#pragma unroll
        for (int s = 32; s > 0; s >>= 1) acc += __shfl_xor(acc, s, 64);
        lg[e] = acc;
    }

    float m = lg[0];
#pragma unroll
    for (int e = 1; e < E_; ++e) m = fmaxf(m, lg[e]);
    float p[E_], s = 0.f;
#pragma unroll
    for (int e = 0; e < E_; ++e) { p[e] = expf(lg[e] - m); s += p[e]; }
    const float inv = 1.f / s;

    int e0 = 0; float p0 = p[0];
#pragma unroll
    for (int e = 1; e < E_; ++e) if (p[e] > p0) { p0 = p[e]; e0 = e; }
    int e1 = -1; float p1 = -1.f;
#pragma unroll
    for (int e = 0; e < E_; ++e) if (e != e0 && p[e] > p1) { p1 = p[e]; e1 = e; }

    if (lane == 0) {
        idx[tok * 2 + 0] = e0;  gate[tok * 2 + 0] = p0 * inv;
        idx[tok * 2 + 1] = e1;  gate[tok * 2 + 1] = p1 * inv;
    }
}

// ---------------------------------------------------------------------------
// 2. Build: fixed SEG-sized segments per expert; meta[e] = clamped count
// ---------------------------------------------------------------------------
__global__ void build_kernel(const int* __restrict__ idx, const float* __restrict__ gate,
                             int* __restrict__ rowmap, float* __restrict__ rowgate,
                             int* __restrict__ posOf, int* __restrict__ meta) {
    __shared__ int cur[E_];
    const int t = threadIdx.x;             // 256
    if (t < E_) cur[t] = 0;
    __syncthreads();
    for (int i = t; i < MAXROWS; i += 256) { rowmap[i] = 0; rowgate[i] = 0.f; }
    __syncthreads();
    for (int i = t; i < NROWS; i += 256) {
        const int e = idx[i];
        const int o = atomicAdd(&cur[e], 1);
        if (o < SEG) {
            const int pos = e * SEG + o;
            rowmap[pos]  = i >> 1;
            rowgate[pos] = gate[i];
            posOf[i]     = pos;
        } else {
            posOf[i] = e * SEG;            // ~8-sigma overflow; degrade gracefully
        }
    }
    __syncthreads();
    if (t < E_) meta[t] = cur[t] < SEG ? cur[t] : SEG;
}

// ---------------------------------------------------------------------------
// 3. Gather x rows into bf16 Xg
// ---------------------------------------------------------------------------
__global__ void gather_kernel(const float* __restrict__ x, const int* __restrict__ rowmap,
                              unsigned short* __restrict__ Xg) {
    const int g = blockIdx.x * 256 + threadIdx.x;
    const int pos = g / (D_ / 8), c = g % (D_ / 8);
    const int tok = rowmap[pos];
    const float* src = x + (size_t)tok * D_ + c * 8;
    f32x4 a = *(const f32x4*)src;
    f32x4 b = *(const f32x4*)(src + 4);
    u16x8 o;
    o[0] = f2bf(a[0]); o[1] = f2bf(a[1]); o[2] = f2bf(a[2]); o[3] = f2bf(a[3]);
    o[4] = f2bf(b[0]); o[5] = f2bf(b[1]); o[6] = f2bf(b[2]); o[7] = f2bf(b[3]);
    *(u16x8*)(Xg + (size_t)pos * D_ + c * 8) = o;
}

// ---------------------------------------------------------------------------
// 4/5. Per-expert GEMM, reg-staged double-buffered, 2 blocks/CU.
//   LDS rows = 32 bf16 (64 B, 4 x 16B slots); phys slot = logical ^ ((row>>1)&3)
//   -> exact 128 B/cyc bank coverage for frag reads and staging writes.
//   Per K-step: issue A(3xb128) + B(<=2xf32x4) loads for k+1; compute k;
//   cvt+write k+1; barrier. Grid bid = ((split<<NNSH | n) << 4) | e.
//   EPI=0: +bias, exact gelu -> bf16 H.  EPI=1: (+bias if split0)*gate ->
//   bf16 plane (plane0 = C0, planes 1.. = C123 + (split-1)*MAXROWS*N).
// ---------------------------------------------------------------------------
template <int EPI, int NNSH, int KLEN>
__global__ __launch_bounds__(512, 4)
void gemm_kernel(const unsigned short* __restrict__ Ag, const float* __restrict__ Bw,
                 const float* __restrict__ bias, unsigned short* __restrict__ C0,
                 unsigned short* __restrict__ C123, const float* __restrict__ rowgate,
                 const int* __restrict__ meta, const int K, const int N) {
    constexpr int NT = KLEN / BK;          // 24

    const int bid   = blockIdx.x;
    const int e     = bid & 15;
    const int rest  = bid >> 4;
    const int n     = rest & ((1 << NNSH) - 1);
    const int split = rest >> NNSH;
    const int m0    = e * SEG;
    const int n0    = n * BNW;
    const int kOff  = split * KLEN;

    __shared__ alignas(16) unsigned short As[2][SEG * BK];   // 2 x 24 KB
    __shared__ alignas(16) unsigned short Bs[2][BNW * BK];   // 2 x 6 KB

    const int t    = threadIdx.x;          // 512
    const int lane = t & 63;
    const int wv   = t >> 6;               // 0..7
    const int wm   = wv >> 1;              // 0..3 : 96-row band
    const int wn   = wv & 1;               // 0..1 : 48-col slice
    const int r16  = lane & 15;
    const int h    = lane >> 4;            // 0..3
    const int co   = ((h ^ ((r16 >> 1) & 3)) * 8);   // swizzled frag offset (ushort)

    const int  cnt = meta[e];
    const bool act = (wm * 96) < cnt;      // wave-uniform pad-band skip

    f32x4 acc[6][3];
#pragma unroll
    for (int i = 0; i < 6; ++i)
#pragma unroll
        for (int j = 0; j < 3; ++j) acc[i][j] = (f32x4){0.f, 0.f, 0.f, 0.f};

    // ---- A staging: 384 rows x 4 slots(16B) = 1536 slots, 3/thread ----
    unsigned aByte[3];  int aPhys[3];
#pragma unroll
    for (int i = 0; i < 3; ++i) {
        const int c = t + 512 * i, r = c >> 2, s = c & 3;
        aByte[i] = (unsigned)(((m0 + r) * K + kOff + s * 8) * 2);
        aPhys[i] = r * 32 + ((s ^ ((r >> 1) & 3)) * 8);
    }
    // ---- B staging: 96 rows x 8 fp32-slots(16B) = 768 slots; t<512 -> slot t,
    //      t<256 -> also slot 512+t (wave-uniform split: waves 0-3 do 2) ----
    unsigned bByte[2];  int bOff[2];
#pragma unroll
    for (int i = 0; i < 2; ++i) {
        const int sB = t + 512 * i;
        const int r = sB >> 3, c = sB & 7;
        bByte[i] = (unsigned)((((e * N) + n0 + r) * (size_t)K + kOff + c * 4) * 4);
        bOff[i]  = r * 32 + ((((c >> 1) ^ ((r >> 1) & 3))) * 8) + (c & 1) * 4;
    }
    const bool b2 = (t < 256);

    u32x4 areg[3];
    f32x4 breg[2];

    auto loadA = [&](int kt) {
#pragma unroll
        for (int i = 0; i < 3; ++i)
            areg[i] = *(const u32x4*)((const char*)Ag + aByte[i] + kt * (BK * 2));
    };
    auto loadB = [&](int kt) {
        breg[0] = *(const f32x4*)((const char*)Bw + bByte[0] + kt * (BK * 4));
        if (b2) breg[1] = *(const f32x4*)((const char*)Bw + bByte[1] + kt * (BK * 4));
    };
    auto writeA = [&](int buf) {
#pragma unroll
        for (int i = 0; i < 3; ++i)
            *(u32x4*)&As[buf][aPhys[i]] = areg[i];
    };
    auto writeB = [&](int buf) {
        u32x2 q;
        q[0] = cvt_pk_bf16(breg[0][0], breg[0][1]);
        q[1] = cvt_pk_bf16(breg[0][2], breg[0][3]);
        *(u32x2*)&Bs[buf][bOff[0]] = q;
        if (b2) {
            q[0] = cvt_pk_bf16(breg[1][0], breg[1][1]);
            q[1] = cvt_pk_bf16(breg[1][2], breg[1][3]);
            *(u32x2*)&Bs[buf][bOff[1]] = q;
        }
    };
    auto compute = [&](int buf) {
        if (!act) return;
        v8bf bfr[3];
#pragma unroll
        for (int nf = 0; nf < 3; ++nf)
            bfr[nf] = *(const v8bf*)&Bs[buf][(wn * 48 + nf * 16 + r16) * 32 + co];
#pragma unroll
        for (int mf = 0; mf < 6; ++mf) {
            const v8bf af = *(const v8bf*)&As[buf][(wm * 96 + mf * 16 + r16) * 32 + co];
#pragma unroll
            for (int nf = 0; nf < 3; ++nf)
                acc[mf][nf] = __builtin_amdgcn_mfma_f32_16x16x32_bf16(
                    af, bfr[nf], acc[mf][nf], 0, 0, 0);
        }
    };

    // prologue: stage tile 0
    loadA(0); loadB(0);
    writeA(0); writeB(0);
    __syncthreads();

    int cb = 0;
    for (int kt = 0; kt < NT; ++kt) {
        if (kt + 1 < NT) { loadB(kt + 1); loadA(kt + 1); }  // issue early (T14)
        compute(cb);
        if (kt + 1 < NT) { writeA(cb ^ 1); writeB(cb ^ 1); } // write late
        __syncthreads();
        cb ^= 1;
    }

    // epilogue: C/D layout col = lane&15, row = (lane>>4)*4 + reg
    if (!act) return;
    unsigned short* myC = (EPI == 0 || split == 0)
                        ? C0 : C123 + (size_t)(split - 1) * MAXROWS * N;
#pragma unroll
    for (int mf = 0; mf < 6; ++mf) {
#pragma unroll
        for (int jj = 0; jj < 4; ++jj) {
            const int rr = m0 + wm * 96 + mf * 16 + h * 4 + jj;
            float gt = 0.f;
            if (EPI == 1) gt = rowgate[rr];
#pragma unroll
            for (int nf = 0; nf < 3; ++nf) {
                const int cc = n0 + wn * 48 + nf * 16 + r16;
                float v = acc[mf][nf][jj];
                if (EPI == 0) {
                    v += bias[e * N + cc];
                    const float ge = 0.5f * v * (1.f + erff(v * 0.70710678118654752f));
                    myC[(size_t)rr * N + cc] = f2bf(ge);
                } else {
                    if (split == 0) v += bias[e * N + cc];
                    myC[(size_t)rr * N + cc] = f2bf(v * gt);
                }
            }
        }
    }
}

// ---------------------------------------------------------------------------
// 6. Combine: out = x + sum_s (Yp_s[p0] + Yp_s[p1])
// ---------------------------------------------------------------------------
__global__ void combine_kernel(const float* __restrict__ x,
                               const unsigned short* __restrict__ Yp0,
                               const unsigned short* __restrict__ Yp123,
                               const int* __restrict__ posOf, float* __restrict__ out,
                               const int nsplit) {
    const int tok = blockIdx.x;
    const int t   = threadIdx.x;           // 192 * 4 = 768
    const int p0 = posOf[tok * 2 + 0];
    const int p1 = posOf[tok * 2 + 1];
    f32x4 v = *(const f32x4*)(x + (size_t)tok * D_ + t * 4);
    for (int s = 0; s < nsplit; ++s) {
        const unsigned short* base = (s == 0) ? Yp0
                                   : Yp123 + (size_t)(s - 1) * MAXROWS * D_;
        const unsigned short* a = base + (size_t)p0 * D_ + t * 4;
        const unsigned short* b = base + (size_t)p1 * D_ + t * 4;
#pragma unroll
        for (int i = 0; i < 4; ++i) {
            v[i] += __builtin_bit_cast(float, (unsigned)a[i] << 16);
            v[i] += __builtin_bit_cast(float, (unsigned)b[i] << 16);
        }
    }
    *(f32x4*)(out + (size_t)tok * D_ + t * 4) = v;
}

// ---------------------------------------------------------------------------
extern "C" void kernel_launch(void* const* d_in, const int* in_sizes, int n_in,
                              void* d_out, int out_size, void* d_ws, size_t ws_size,
                              hipStream_t stream) {
    const float* x  = (const float*)d_in[0];
    const float* wr = (const float*)d_in[1];
    const float* w1 = (const float*)d_in[2];
    const float* b1 = (const float*)d_in[3];
    const float* w2 = (const float*)d_in[4];
    const float* b2 = (const float*)d_in[5];
    float* out = (float*)d_out;

    char* wsp = (char*)d_ws;
    int*            idxP    = (int*)(wsp + 0);
    float*          gateP   = (float*)(wsp + 16384);
    int*            posOf   = (int*)(wsp + 32768);
    int*            rowmap  = (int*)(wsp + 49152);
    float*          rowgate = (float*)(wsp + 73728);
    int*            meta    = (int*)(wsp + 98304);
    const size_t    XG_OFF  = 131072;
    const size_t    PLANE   = (size_t)MAXROWS * D_ * 2;        // 9.44 MB
    const size_t    H_OFF   = XG_OFF + PLANE;
    const size_t    H_BYTES = (size_t)MAXROWS * F_ * 2;        // 37.75 MB
    unsigned short* Xg    = (unsigned short*)(wsp + XG_OFF);
    unsigned short* H     = (unsigned short*)(wsp + H_OFF);
    unsigned short* Yp0   = Xg;                                // plane 0 overlays Xg
    unsigned short* Yp123 = (unsigned short*)(wsp + H_OFF + H_BYTES);

    const bool split4 = (ws_size >= H_OFF + H_BYTES + 3 * PLANE);  // ~75.6 MB

    router_kernel<<<NTOK, 64, 0, stream>>>(x, wr, idxP, gateP);
    build_kernel<<<1, 256, 0, stream>>>(idxP, gateP, rowmap, rowgate, posOf, meta);
    gather_kernel<<<MAXROWS * (D_ / 8) / 256, 256, 0, stream>>>(x, rowmap, Xg);

    // fc1: K=768, N=3072, 32 n-slices of 96. grid 512 x 512thr, 2 blocks/CU
    gemm_kernel<0, 5, 768><<<E_ * 32, 512, 0, stream>>>(
        Xg, w1, b1, H, (unsigned short*)nullptr, rowgate, meta, D_, F_);

    if (split4) {
        // fc2: K=3072 as 4x768 k-splits, 8 n-slices -> ONE grid of 512 blocks
        gemm_kernel<1, 3, 768><<<E_ * 8 * 4, 512, 0, stream>>>(
            H, w2, b2, Yp0, Yp123, rowgate, meta, F_, D_);
        combine_kernel<<<NTOK, 192, 0, stream>>>(x, Yp0, Yp123, posOf, out, 4);
    } else {
        // fallback: full K in one pass, grid 128 (split decodes to 0)
        gemm_kernel<1, 3, 3072><<<E_ * 8, 512, 0, stream>>>(
            H, w2, b2, Yp0, Yp123, rowgate, meta, F_, D_);
        combine_kernel<<<NTOK, 192, 0, stream>>>(x, Yp0, Yp123, posOf, out, 1);
    }
}

// Round 8
// 210.241 us; speedup vs baseline: 1.5375x; 1.5375x over previous
//
#include <hip/hip_runtime.h>

// ---------------------------------------------------------------------------
// MoE top-2 sparse. MI355X (gfx950). B=2,L=1024,D=768,E=16,F=3072,K=2
// GEMM: m97-proportioned blocks. 256 thr (4 waves 2x2), tile 128x128, BK=64,
// wave tile 64x64 (4x4 frags of mfma_f32_16x16x32_bf16). LDS 64 KB dbuf ->
// 2 blocks/CU, large grid (1152 / 288) with block turnover (the R4-R7
// lockstep grids sat at the 334 TF 2-barrier ceiling; constant ~17k cyc/step).
// A (bf16) via global_load_lds w=16, pre-swizzled source (R4-verified,
// 0 bank conflicts). B (fp32 weights) reg-staged: 32B pair loads -> cvt_pk ->
// one swizzled ds_write_b128. SEG=384 = 3 M-tiles/expert; the 3 buddies
// sharing a weight slice sit on one XCD (bid%8 == e%8) -> weights ~1x HBM.
// fc2: no k-split (288 blocks fill chip), Y plain fp32.
// ---------------------------------------------------------------------------

#define D_      768
#define E_      16
#define F_      3072
#define NTOK    2048
#define NROWS   4096
#define SEG     384
#define MAXROWS 6144
#define BK      64

typedef __attribute__((ext_vector_type(4))) unsigned int   u32x4;
typedef __attribute__((ext_vector_type(8))) unsigned short u16x8;
typedef __attribute__((ext_vector_type(8))) short          v8bf;
typedef __attribute__((ext_vector_type(4))) float          f32x4;

static __device__ inline unsigned short f2bf(float f) {
    unsigned u = __builtin_bit_cast(unsigned, f);
    u += 0x7fffu + ((u >> 16) & 1u);      // RNE
    return (unsigned short)(u >> 16);
}
static __device__ __forceinline__ unsigned cvt_pk_bf16(float lo, float hi) {
    unsigned r;
    asm("v_cvt_pk_bf16_f32 %0, %1, %2" : "=v"(r) : "v"(lo), "v"(hi));
    return r;
}
static __device__ __forceinline__ void gll16(const void* g, void* l) {
    __builtin_amdgcn_global_load_lds(
        (const __attribute__((address_space(1))) unsigned int*)g,
        (__attribute__((address_space(3))) unsigned int*)l, 16, 0, 0);
}

// ---------------------------------------------------------------------------
// 1. Router: softmax over 16, top-2 (ties -> lowest idx), gates = raw probs
// ---------------------------------------------------------------------------
__global__ void router_kernel(const float* __restrict__ x, const float* __restrict__ wr,
                              int* __restrict__ idx, float* __restrict__ gate) {
    const int tok  = blockIdx.x;
    const int lane = threadIdx.x;          // 64
    const float* xr = x + (size_t)tok * D_;

    float xv[12];
#pragma unroll
    for (int j = 0; j < 12; ++j) xv[j] = xr[lane + 64 * j];

    float lg[E_];
#pragma unroll
    for (int e = 0; e < E_; ++e) {
        const float* w = wr + (size_t)e * D_;
        float acc = 0.f;
#pragma unroll
        for (int j = 0; j < 12; ++j) acc += xv[j] * w[lane + 64 * j];
#pragma unroll
        for (int s = 32; s > 0; s >>= 1) acc += __shfl_xor(acc, s, 64);
        lg[e] = acc;
    }

    float m = lg[0];
#pragma unroll
    for (int e = 1; e < E_; ++e) m = fmaxf(m, lg[e]);
    float p[E_], s = 0.f;
#pragma unroll
    for (int e = 0; e < E_; ++e) { p[e] = expf(lg[e] - m); s += p[e]; }
    const float inv = 1.f / s;

    int e0 = 0; float p0 = p[0];
#pragma unroll
    for (int e = 1; e < E_; ++e) if (p[e] > p0) { p0 = p[e]; e0 = e; }
    int e1 = -1; float p1 = -1.f;
#pragma unroll
    for (int e = 0; e < E_; ++e) if (e != e0 && p[e] > p1) { p1 = p[e]; e1 = e; }

    if (lane == 0) {
        idx[tok * 2 + 0] = e0;  gate[tok * 2 + 0] = p0 * inv;
        idx[tok * 2 + 1] = e1;  gate[tok * 2 + 1] = p1 * inv;
    }
}

// ---------------------------------------------------------------------------
// 2. Build: fixed SEG-sized segments per expert; meta[e] = clamped count
// ---------------------------------------------------------------------------
__global__ void build_kernel(const int* __restrict__ idx, const float* __restrict__ gate,
                             int* __restrict__ rowmap, float* __restrict__ rowgate,
                             int* __restrict__ posOf, int* __restrict__ meta) {
    __shared__ int cur[E_];
    const int t = threadIdx.x;             // 256
    if (t < E_) cur[t] = 0;
    __syncthreads();
    for (int i = t; i < MAXROWS; i += 256) { rowmap[i] = 0; rowgate[i] = 0.f; }
    __syncthreads();
    for (int i = t; i < NROWS; i += 256) {
        const int e = idx[i];
        const int o = atomicAdd(&cur[e], 1);
        if (o < SEG) {
            const int pos = e * SEG + o;
            rowmap[pos]  = i >> 1;
            rowgate[pos] = gate[i];
            posOf[i]     = pos;
        } else {
            posOf[i] = e * SEG;            // ~8-sigma overflow; degrade gracefully
        }
    }
    __syncthreads();
    if (t < E_) meta[t] = cur[t] < SEG ? cur[t] : SEG;
}

// ---------------------------------------------------------------------------
// 3. Gather x rows into bf16 Xg
// ---------------------------------------------------------------------------
__global__ void gather_kernel(const float* __restrict__ x, const int* __restrict__ rowmap,
                              unsigned short* __restrict__ Xg) {
    const int g = blockIdx.x * 256 + threadIdx.x;
    const int pos = g / (D_ / 8), c = g % (D_ / 8);
    const int tok = rowmap[pos];
    const float* src = x + (size_t)tok * D_ + c * 8;
    f32x4 a = *(const f32x4*)src;
    f32x4 b = *(const f32x4*)(src + 4);
    u16x8 o;
    o[0] = f2bf(a[0]); o[1] = f2bf(a[1]); o[2] = f2bf(a[2]); o[3] = f2bf(a[3]);
    o[4] = f2bf(b[0]); o[5] = f2bf(b[1]); o[6] = f2bf(b[2]); o[7] = f2bf(b[3]);
    *(u16x8*)(Xg + (size_t)pos * D_ + c * 8) = o;
}

// ---------------------------------------------------------------------------
// 4/5. 128x128 GEMM block, m97 proportions.
//   LDS rows = 64 bf16 (128 B = 8 x 16B slots); phys slot = logical ^ (row&7).
//   A: 4 global_load_lds(16B)/thread, source pre-swizzled. B: 4 x 32B fp32
//   pair loads -> 2 cvt_pk x4 -> 4 swizzled ds_write_b128 (bank-balanced).
//   Decode: b%8 = e%8 (XCD pin); j=b>>3: e = b%8 + 8*(j/(3*NTl));
//   jj=j%(3*NTl); nt=jj/3; mtl=jj%3. m0 = e*SEG + mtl*128, n0 = nt*128.
//   EPI=0: +bias, exact gelu -> bf16 H.  EPI=1: (+bias)*rowgate -> fp32 Y.
// ---------------------------------------------------------------------------
template <int EPI>
__global__ __launch_bounds__(256, 2)
void gemm_kernel(const unsigned short* __restrict__ Ag, const float* __restrict__ Bw,
                 const float* __restrict__ bias, void* __restrict__ Cout,
                 const float* __restrict__ rowgate, const int* __restrict__ meta,
                 const int K, const int N, const int NTl) {
    const int b   = blockIdx.x;
    const int j   = b >> 3;
    const int per = 3 * NTl;
    const int e   = (b & 7) + 8 * (j / per);
    const int jj  = j % per;
    const int nt  = jj / 3;
    const int mtl = jj % 3;

    const int cnt = meta[e];
    if (mtl * 128 >= cnt) return;          // whole block is padding
    const int m0 = e * SEG + mtl * 128;
    const int n0 = nt * 128;

    __shared__ alignas(16) unsigned short As[2][128 * 64];   // 2 x 16 KB
    __shared__ alignas(16) unsigned short Bs[2][128 * 64];   // 2 x 16 KB

    const int t    = threadIdx.x;          // 256
    const int lane = t & 63;
    const int wv   = t >> 6;               // 0..3
    const int wm   = wv >> 1;              // 0..1 : 64-row half
    const int wn   = wv & 1;               // 0..1 : 64-col half
    const int r16  = lane & 15;
    const int h    = lane >> 4;            // 0..3

    const bool act = (mtl * 128 + wm * 64) < cnt;   // wave-band pad skip

    f32x4 acc[4][4];
#pragma unroll
    for (int i = 0; i < 4; ++i)
#pragma unroll
        for (int q = 0; q < 4; ++q) acc[i][q] = (f32x4){0.f, 0.f, 0.f, 0.f};

    // ---- A staging (global_load_lds, pre-swizzled source; R4-verified) ----
    // chunk j2: lane L covers row wv*32 + j2*8 + (L>>3); its linear 16B dest
    // slot (L&7) must hold logical slot (L&7)^((L>>3)&7).
    const int aRowL = wv * 32 + (lane >> 3);
    const int aColE = (((lane & 7) ^ ((lane >> 3) & 7)) << 3);
    const unsigned short* Asrc = Ag + (size_t)(m0 + aRowL) * K + aColE;

    // ---- B staging: pair P = t + 256*i (i=0..3). row = P>>3 (B output col),
    // pc = P&7 (16B bf16 slot after cvt). 32B fp32 contiguous per pair.
    const float* pB[4];  int bOff[4];
#pragma unroll
    for (int i = 0; i < 4; ++i) {
        const int P = t + 256 * i, row = P >> 3, pc = P & 7;
        pB[i]   = Bw + ((size_t)e * N + n0 + row) * K + pc * 8;
        bOff[i] = row * 64 + ((pc ^ (row & 7)) << 3);
    }

    f32x4 blo[4], bhi[4];

    auto stageA = [&](int buf, int kt) {
#pragma unroll
        for (int j2 = 0; j2 < 4; ++j2)
            gll16(Asrc + (size_t)(j2 * 8) * K + kt * BK,
                  &As[buf][(wv * 32 + j2 * 8) * 64]);
    };
    auto loadB = [&](int kt) {
#pragma unroll
        for (int i = 0; i < 4; ++i) {
            const float* p = pB[i] + kt * BK;
            blo[i] = *(const f32x4*)p;
            bhi[i] = *(const f32x4*)(p + 4);
        }
    };
    auto writeB = [&](int buf) {
#pragma unroll
        for (int i = 0; i < 4; ++i) {
            u32x4 q;
            q[0] = cvt_pk_bf16(blo[i][0], blo[i][1]);
            q[1] = cvt_pk_bf16(blo[i][2], blo[i][3]);
            q[2] = cvt_pk_bf16(bhi[i][0], bhi[i][1]);
            q[3] = cvt_pk_bf16(bhi[i][2], bhi[i][3]);
            *(u32x4*)&Bs[buf][bOff[i]] = q;
        }
    };
    auto compute = [&](int buf) {
        if (!act) return;
#pragma unroll
        for (int ks = 0; ks < 2; ++ks) {
            v8bf bfr[4], af[4];
#pragma unroll
            for (int nf = 0; nf < 4; ++nf) {
                const int R = wn * 64 + nf * 16 + r16;
                bfr[nf] = *(const v8bf*)&Bs[buf][R * 64 + (((ks * 4 + h) ^ (r16 & 7)) << 3)];
            }
#pragma unroll
            for (int mf = 0; mf < 4; ++mf) {
                const int R = wm * 64 + mf * 16 + r16;
                af[mf] = *(const v8bf*)&As[buf][R * 64 + (((ks * 4 + h) ^ (r16 & 7)) << 3)];
            }
#pragma unroll
            for (int mf = 0; mf < 4; ++mf)
#pragma unroll
                for (int nf = 0; nf < 4; ++nf)
                    acc[mf][nf] = __builtin_amdgcn_mfma_f32_16x16x32_bf16(
                        af[mf], bfr[nf], acc[mf][nf], 0, 0, 0);
        }
    };

    const int NS = K / BK;
    stageA(0, 0); loadB(0); writeB(0);
    __syncthreads();
    int cb = 0;
    for (int kt = 0; kt < NS; ++kt) {
        if (kt + 1 < NS) { stageA(cb ^ 1, kt + 1); loadB(kt + 1); }  // issue early
        compute(cb);
        if (kt + 1 < NS) writeB(cb ^ 1);                             // write late
        __syncthreads();
        cb ^= 1;
    }

    // ---- epilogue: C/D layout col = lane&15, row = (lane>>4)*4 + reg ----
    if (!act) return;
#pragma unroll
    for (int mf = 0; mf < 4; ++mf) {
#pragma unroll
        for (int q = 0; q < 4; ++q) {
            const int rr = m0 + wm * 64 + mf * 16 + h * 4 + q;
            float gt = 0.f;
            if (EPI == 1) gt = rowgate[rr];
#pragma unroll
            for (int nf = 0; nf < 4; ++nf) {
                const int cc = n0 + wn * 64 + nf * 16 + r16;
                float v = acc[mf][nf][q] + bias[e * N + cc];
                if (EPI == 0) {
                    const float ge = 0.5f * v * (1.f + erff(v * 0.70710678118654752f));
                    ((unsigned short*)Cout)[(size_t)rr * N + cc] = f2bf(ge);
                } else {
                    ((float*)Cout)[(size_t)rr * N + cc] = v * gt;
                }
            }
        }
    }
}

// ---------------------------------------------------------------------------
// 6. Combine: out = x + Y[p0] + Y[p1]   (Y already gate-scaled, fp32)
// ---------------------------------------------------------------------------
__global__ void combine_kernel(const float* __restrict__ x, const float* __restrict__ Y,
                               const int* __restrict__ posOf, float* __restrict__ out) {
    const int tok = blockIdx.x;
    const int t   = threadIdx.x;           // 192 * 4 = 768
    const int p0 = posOf[tok * 2 + 0];
    const int p1 = posOf[tok * 2 + 1];
    f32x4 v = *(const f32x4*)(x + (size_t)tok * D_ + t * 4);
    v += *(const f32x4*)(Y + (size_t)p0 * D_ + t * 4);
    v += *(const f32x4*)(Y + (size_t)p1 * D_ + t * 4);
    *(f32x4*)(out + (size_t)tok * D_ + t * 4) = v;
}

// ---------------------------------------------------------------------------
extern "C" void kernel_launch(void* const* d_in, const int* in_sizes, int n_in,
                              void* d_out, int out_size, void* d_ws, size_t ws_size,
                              hipStream_t stream) {
    const float* x  = (const float*)d_in[0];
    const float* wr = (const float*)d_in[1];
    const float* w1 = (const float*)d_in[2];
    const float* b1 = (const float*)d_in[3];
    const float* w2 = (const float*)d_in[4];
    const float* b2 = (const float*)d_in[5];
    float* out = (float*)d_out;

    char* wsp = (char*)d_ws;
    int*            idxP    = (int*)(wsp + 0);
    float*          gateP   = (float*)(wsp + 16384);
    int*            posOf   = (int*)(wsp + 32768);
    int*            rowmap  = (int*)(wsp + 49152);
    float*          rowgate = (float*)(wsp + 73728);
    int*            meta    = (int*)(wsp + 98304);
    const size_t    XG_OFF  = 131072;
    const size_t    XG_B    = (size_t)MAXROWS * D_ * 2;       // 9.44 MB
    const size_t    H_OFF   = XG_OFF + XG_B;
    const size_t    H_B     = (size_t)MAXROWS * F_ * 2;       // 37.75 MB
    const size_t    Y_OFF   = H_OFF + H_B;
    unsigned short* Xg = (unsigned short*)(wsp + XG_OFF);
    unsigned short* H  = (unsigned short*)(wsp + H_OFF);
    float*          Y  = (float*)(wsp + Y_OFF);               // 18.87 MB

    router_kernel<<<NTOK, 64, 0, stream>>>(x, wr, idxP, gateP);
    build_kernel<<<1, 256, 0, stream>>>(idxP, gateP, rowmap, rowgate, posOf, meta);
    gather_kernel<<<MAXROWS * (D_ / 8) / 256, 256, 0, stream>>>(x, rowmap, Xg);

    // fc1: K=768 (12 steps), N=3072, NTl=24 -> grid 16*24*3 = 1152
    gemm_kernel<0><<<16 * 24 * 3, 256, 0, stream>>>(
        Xg, w1, b1, (void*)H, rowgate, meta, D_, F_, 24);

    // fc2: K=3072 (48 steps), N=768, NTl=6 -> grid 16*6*3 = 288, no k-split
    gemm_kernel<1><<<16 * 6 * 3, 256, 0, stream>>>(
        H, w2, b2, (void*)Y, rowgate, meta, F_, D_, 6);

    combine_kernel<<<NTOK, 192, 0, stream>>>(x, Y, posOf, out);
}